// Round 10
// baseline (416.103 us; speedup 1.0000x reference)
//
#include <hip/hip_runtime.h>

typedef int   i32x8 __attribute__((ext_vector_type(8)));
typedef float f32x4 __attribute__((ext_vector_type(4)));

#define B_   8
#define N_   4096
#define D_   256

// fp8 fragment-major blob layout:
//   blob[g16][kt][h] = 1 KB chunk; lane l's 16 bytes at +l*16 hold
//   P[g16*16 + (l&15)][k = kt*128 + (l>>4)*32 + h*16 .. +16]  (e4m3)

__device__ __forceinline__ void gl_lds16(const void* g, void* l) {
  __builtin_amdgcn_global_load_lds(
      (const __attribute__((address_space(1))) unsigned int*)g,
      (__attribute__((address_space(3))) unsigned int*)l, 16, 0, 0);
}

// sum of squares of the 4 e4m3 bytes in w (selector must be a literal)
__device__ __forceinline__ float sq8(unsigned w) {
  float f0 = __builtin_amdgcn_cvt_f32_fp8(w, 0);
  float f1 = __builtin_amdgcn_cvt_f32_fp8(w, 1);
  float f2 = __builtin_amdgcn_cvt_f32_fp8(w, 2);
  float f3 = __builtin_amdgcn_cvt_f32_fp8(w, 3);
  return f0 * f0 + f1 * f1 + f2 * f2 + f3 * f3;
}

// One wave per 16-row group: fp32 -> fp8 e4m3 convert (coalesced 1 KB float4
// reads), in-wave LDS transpose to fragment-major, norms of DEQUANTIZED
// values accumulated during readback, min-init.
__global__ __launch_bounds__(256) void prep_kernel(
    const float* __restrict__ x, const float* __restrict__ y,
    unsigned char* __restrict__ Xf, unsigned char* __restrict__ Yf,
    float* __restrict__ xx, float* __restrict__ yy,
    unsigned* __restrict__ rowmin, unsigned* __restrict__ colmin,
    float* __restrict__ out)
{
  __shared__ unsigned char T[4][16 * 272];   // 16 rows x 256B fp8 (+16 pad)
  if (blockIdx.x == 0 && threadIdx.x == 0) out[0] = 0.f;

  const int wv = threadIdx.x >> 6, lane = threadIdx.x & 63;
  const int wid = (blockIdx.x << 2) + wv;          // 0..4095

  const float* src; unsigned char* dst; float* nrm; unsigned* mn; int g;
  if (wid < 2048) { g = wid;        src = x; dst = Xf; nrm = xx; mn = rowmin; }
  else            { g = wid - 2048; src = y; dst = Yf; nrm = yy; mn = colmin; }

  unsigned char* tw = T[wv];
  const float* rp = src + (size_t)g * 16 * D_;
#pragma unroll
  for (int r = 0; r < 16; ++r) {
    float4 v = *(const float4*)(rp + r * D_ + lane * 4);   // 1 KB contiguous
    unsigned u = __builtin_amdgcn_cvt_pk_fp8_f32(v.x, v.y, 0, 0);
    u = __builtin_amdgcn_cvt_pk_fp8_f32(v.z, v.w, u, 1);   // bytes = x,y,z,w
    *(unsigned*)(tw + r * 272 + lane * 4) = u;
  }
  // Each wave only reads its own T[wv] slice; all cross-lane traffic is
  // intra-wave, so a wave-local lgkmcnt drain replaces the 4-wave rendezvous.
  asm volatile("s_waitcnt lgkmcnt(0)" ::: "memory");
  __builtin_amdgcn_wave_barrier();

  // fragment-order readback: row = lane&15, k-base = (lane>>4)*32
  float s = 0.f;
  const int row = lane & 15, ko = (lane >> 4) * 32;
#pragma unroll
  for (int kt = 0; kt < 2; ++kt)
#pragma unroll
    for (int h = 0; h < 2; ++h) {
      uint4 c = *(const uint4*)(tw + row * 272 + kt * 128 + ko + h * 16);
      s += sq8(c.x) + sq8(c.y) + sq8(c.z) + sq8(c.w);
      *(uint4*)(dst + ((((size_t)g * 2 + kt) * 2 + h) << 10) + lane * 16) = c;
    }
  s += __shfl_xor(s, 16, 64);   // fold quads: row (lane&15)'s full norm
  s += __shfl_xor(s, 32, 64);
  if      (lane < 16) nrm[g * 16 + lane] = s;
  else if (lane < 32) mn[g * 16 + lane - 16] = 0x7f800000u;   // +inf
}

// MX-fp8 chamfer GEMM (mfma_scale_f32_16x16x128_f8f6f4, scales = 1.0).
// Round-20: VALU diet. Ten rounds established the empirical law
// dur = (T_mfma + T_valu) / 0.69: MfmaUtil+VALUBusy caps at ~69% across
// every structure (issue arbitration); T_mfma = 14.7 us is the data floor;
// the only lever left is T_valu (15.5 us = ~287 insts/ct-wave vs ~100
// essential). This round: (1) setprio REMOVED (m190: hurts lockstep GEMM;
// all our T5 attempts nulled); (2) ct loop fully unrolled (ds offsets ->
// immediates, load bases -> SALU adds); (3) epilogue in min3-fusable form:
// rmin = fminf(fminf(rmin,v0),v1) -> v_min3, colmin chains eat 2 vals/step
// -> v_min3, both j's share one xv pass. ~250 -> ~190 insts/ct.
__global__ __launch_bounds__(256, 2) void chamfer_gemm(
    const unsigned char* __restrict__ Xf, const unsigned char* __restrict__ Yf,
    const float* __restrict__ xx, const float* __restrict__ yy,
    unsigned* __restrict__ rowmin, unsigned* __restrict__ colmin)
{
  __shared__ unsigned cmin_s[512];                     // col-min table
  __shared__ float    yys[512];                        // yy slice (LDS, low-lat)

  const int bid = blockIdx.x;
  const int b   = bid & 7;                   // batch == XCD (L2 locality)
  const int rt  = (bid >> 3) & 15;           // 16 row-tiles of 256
  const int cq  = bid >> 7;                  // 0..7 col-eighths of 512
  const int n0  = rt * 256;
  const int m0  = cq * 512;

  const int t = threadIdx.x, lane = t & 63, wave = t >> 6;
  const int quad = lane >> 4, lcol = lane & 15;

  cmin_s[t]       = 0x7f800000u;
  cmin_s[t + 256] = 0x7f800000u;
  const float* yyp = yy + b * N_ + m0;
  if (t < 128)   // 512 floats = 2 KB
    gl_lds16((const unsigned char*)yyp + t * 16, (unsigned char*)yys + t * 16);

  // ---- A fragments -> registers (coalesced dwordx4 from fragment blob) ----
  // wave owns 64 rows: g16 = b*256 + rt*16 + wave*4 + i, i = 0..3
  i32x8 af[4][2];
#pragma unroll
  for (int i = 0; i < 4; ++i) {
    const size_t g = (size_t)(b * 256 + rt * 16 + wave * 4 + i);
#pragma unroll
    for (int kt = 0; kt < 2; ++kt) {
      const uint4* p = (const uint4*)(Xf + ((g * 2 + kt) << 11));
      uint4* h = (uint4*)&af[i][kt];
      h[0] = p[lane];        // h=0
      h[1] = p[64 + lane];   // h=1
    }
  }

  float xv[4][4], rmin[4][4];
  const float* xxp = xx + b * N_ + n0 + wave * 64;
#pragma unroll
  for (int i = 0; i < 4; ++i)
#pragma unroll
    for (int r = 0; r < 4; ++r) {
      xv[i][r] = xxp[i * 16 + quad * 4 + r];
      rmin[i][r] = 1e30f;
    }

  __syncthreads();   // publish cmin init + yys (drains the gl_lds); the ONLY
                     // pre-flush barrier -- the ct loop below has none.

  // B source: ct = 32 cols = 2 contiguous g16 blobs = 8 KB, L2-resident.
  const unsigned char* Ybase = Yf + ((size_t)(b * 256 + cq * 32) << 12);
  const f32x4 z4 = {0.f, 0.f, 0.f, 0.f};   // C-in for kt=0 (no acc zeroing)

  // load one ct's B fragments into a named register set (static indices)
  auto LOADB = [&](i32x8 (&bq)[2][2], int ct) {
    const unsigned char* Yct = Ybase + ((size_t)ct << 13);
#pragma unroll
    for (int j = 0; j < 2; ++j)
#pragma unroll
      for (int kt = 0; kt < 2; ++kt) {
        uint4* h = (uint4*)&bq[j][kt];
        h[0] = *(const uint4*)(Yct + j * 4096 + kt * 2048 + lane * 16);
        h[1] = *(const uint4*)(Yct + j * 4096 + kt * 2048 + 1024 + lane * 16);
      }
  };

  auto COMPUTE = [&](i32x8 (&bq)[2][2], int ct) {
    f32x4 acc[4][2];
#pragma unroll
    for (int i = 0; i < 4; ++i)
#pragma unroll
      for (int j = 0; j < 2; ++j)
        acc[i][j] = __builtin_amdgcn_mfma_scale_f32_16x16x128_f8f6f4(
            af[i][0], bq[j][0], z4,        // kt=0: C = 0 constant
            0, 0, 0, 127, 0, 127);
#pragma unroll
    for (int i = 0; i < 4; ++i)
#pragma unroll
      for (int j = 0; j < 2; ++j)
        acc[i][j] = __builtin_amdgcn_mfma_scale_f32_16x16x128_f8f6f4(
            af[i][1], bq[j][1], acc[i][j], // kt=1: accumulate
            0, 0, 0, 127, 0, 127);

    // epilogue (min3-fusable): C/D row = i*16 + quad*4 + r, col = j*16+lcol
    float yv0 = yys[ct * 32 + lcol];
    float yv1 = yys[ct * 32 + 16 + lcol];
    float cm0 = 1e30f, cm1 = 1e30f;
#pragma unroll
    for (int i = 0; i < 4; ++i)
#pragma unroll
      for (int r = 0; r < 4; r += 2) {       // 2 rows/step -> min3 chains
        float a0 = acc[i][0][r],     a1 = acc[i][1][r];
        float b0 = acc[i][0][r + 1], b1 = acc[i][1][r + 1];
        // rowmin candidates (both j in one min3 with the running value)
        rmin[i][r] = fminf(fminf(rmin[i][r],
                       __builtin_fmaf(-2.f, a0, yv0)),
                       __builtin_fmaf(-2.f, a1, yv1));
        rmin[i][r + 1] = fminf(fminf(rmin[i][r + 1],
                           __builtin_fmaf(-2.f, b0, yv0)),
                           __builtin_fmaf(-2.f, b1, yv1));
        // colmin chains: 2 values per fminf(fminf()) -> v_min3
        float xr = xv[i][r], xs = xv[i][r + 1];
        cm0 = fminf(fminf(cm0, __builtin_fmaf(-2.f, a0, xr)),
                    __builtin_fmaf(-2.f, b0, xs));
        cm1 = fminf(fminf(cm1, __builtin_fmaf(-2.f, a1, xr)),
                    __builtin_fmaf(-2.f, b1, xs));
      }
    // 64-lane fire-and-forget; quads merge inside the one ds_min issue
    atomicMin(&cmin_s[ct * 32 + lcol],      __float_as_uint(cm0 + yv0));
    atomicMin(&cmin_s[ct * 32 + 16 + lcol], __float_as_uint(cm1 + yv1));
  };

  // 2-deep register pipeline: loads for ct+1 issue before ct's MFMA cluster;
  // fully unrolled -> ds offsets/immediates, SALU base updates, no reindex.
  i32x8 bqA[2][2], bqB[2][2];
  LOADB(bqA, 0);
#pragma unroll
  for (int p = 0; p < 8; ++p) {
    const int ct0 = 2 * p, ct1 = 2 * p + 1;
    LOADB(bqB, ct1);
    COMPUTE(bqA, ct0);
    LOADB(bqA, (ct1 + 1) & 15);   // p=7 wraps to ct0 (dead value, in-bounds)
    COMPUTE(bqB, ct1);
  }

  // rowmin: one global atomic set per block (64 rows/wave)
#pragma unroll
  for (int i = 0; i < 4; ++i)
#pragma unroll
    for (int r = 0; r < 4; ++r) {
      float v = xv[i][r] + rmin[i][r];
#pragma unroll
      for (int m = 1; m < 16; m <<= 1) v = fminf(v, __shfl_xor(v, m, 64));
      if (lcol == 0)
        atomicMin(rowmin + b * N_ + n0 + wave * 64 + i * 16 + quad * 4 + r,
                  __float_as_uint(v));
    }

  __syncthreads();
  // colmin: flush LDS table to global
#pragma unroll
  for (int i = 0; i < 2; ++i) {
    int idx = t + i * 256;
    atomicMin(colmin + b * N_ + m0 + idx, cmin_s[idx]);
  }
}

// 64 blocks x 256 threads: 16384 uint4 = 65536 mins; wave-reduce + atomicAdd.
__global__ __launch_bounds__(256) void reduce_kernel(
    const unsigned* __restrict__ mins,   // rowmin then colmin, contiguous
    float* __restrict__ out)
{
  int idx = blockIdx.x * 256 + threadIdx.x;
  uint4 u = ((const uint4*)mins)[idx];
  float s = __uint_as_float(u.x) + __uint_as_float(u.y)
          + __uint_as_float(u.z) + __uint_as_float(u.w);
#pragma unroll
  for (int m = 1; m < 64; m <<= 1) s += __shfl_xor(s, m, 64);
  if ((threadIdx.x & 63) == 0) atomicAdd(out, s);
}

extern "C" void kernel_launch(void* const* d_in, const int* in_sizes, int n_in,
                              void* d_out, int out_size, void* d_ws, size_t ws_size,
                              hipStream_t stream) {
  const float* gts   = (const float*)d_in[0];   // [8,4096,256] fp32
  const float* preds = (const float*)d_in[1];   // [8,4096,256] fp32

  char* ws = (char*)d_ws;
  const size_t XB_BYTES = (size_t)B_ * N_ * D_;         // 8 MiB each (fp8)
  unsigned char* Xf     = (unsigned char*)ws;
  unsigned char* Yf     = (unsigned char*)(ws + XB_BYTES);
  float*    xx     = (float*)(ws + 2 * XB_BYTES);
  float*    yy     = (float*)(ws + 2 * XB_BYTES + (size_t)B_ * N_ * 4);
  unsigned* rowmin = (unsigned*)(ws + 2 * XB_BYTES + (size_t)B_ * N_ * 8);
  unsigned* colmin = (unsigned*)(ws + 2 * XB_BYTES + (size_t)B_ * N_ * 12);

  // 4096 row-groups of 16 (X then Y), one wave each -> 1024 blocks
  prep_kernel<<<1024, 256, 0, stream>>>(gts, preds, Xf, Yf, xx, yy, rowmin, colmin,
                                        (float*)d_out);

  // 8 batches x 16 row-tiles(256) x 8 col-eighths(512) = 1024 blocks
  chamfer_gemm<<<1024, 256, 0, stream>>>(Xf, Yf, xx, yy, rowmin, colmin);

  reduce_kernel<<<64, 256, 0, stream>>>(rowmin, (float*)d_out);
}

// Round 11
// 133.357 us; speedup vs baseline: 3.1202x; 3.1202x over previous
//
#include <hip/hip_runtime.h>

typedef int   i32x8 __attribute__((ext_vector_type(8)));
typedef float f32x4 __attribute__((ext_vector_type(4)));

#define B_   8
#define N_   4096
#define D_   256

// fp8 fragment-major blob layout:
//   blob[g16][kt][h] = 1 KB chunk; lane l's 16 bytes at +l*16 hold
//   P[g16*16 + (l&15)][k = kt*128 + (l>>4)*32 + h*16 .. +16]  (e4m3)

__device__ __forceinline__ void gl_lds16(const void* g, void* l) {
  __builtin_amdgcn_global_load_lds(
      (const __attribute__((address_space(1))) unsigned int*)g,
      (__attribute__((address_space(3))) unsigned int*)l, 16, 0, 0);
}

// sum of squares of the 4 e4m3 bytes in w (selector must be a literal)
__device__ __forceinline__ float sq8(unsigned w) {
  float f0 = __builtin_amdgcn_cvt_f32_fp8(w, 0);
  float f1 = __builtin_amdgcn_cvt_f32_fp8(w, 1);
  float f2 = __builtin_amdgcn_cvt_f32_fp8(w, 2);
  float f3 = __builtin_amdgcn_cvt_f32_fp8(w, 3);
  return f0 * f0 + f1 * f1 + f2 * f2 + f3 * f3;
}

// One wave per 16-row group: fp32 -> fp8 e4m3 convert (coalesced 1 KB float4
// reads), in-wave LDS transpose to fragment-major, norms of DEQUANTIZED
// values accumulated during readback, min-init.
__global__ __launch_bounds__(256) void prep_kernel(
    const float* __restrict__ x, const float* __restrict__ y,
    unsigned char* __restrict__ Xf, unsigned char* __restrict__ Yf,
    float* __restrict__ xx, float* __restrict__ yy,
    unsigned* __restrict__ rowmin, unsigned* __restrict__ colmin,
    float* __restrict__ out)
{
  __shared__ unsigned char T[4][16 * 272];   // 16 rows x 256B fp8 (+16 pad)
  if (blockIdx.x == 0 && threadIdx.x == 0) out[0] = 0.f;

  const int wv = threadIdx.x >> 6, lane = threadIdx.x & 63;
  const int wid = (blockIdx.x << 2) + wv;          // 0..4095

  const float* src; unsigned char* dst; float* nrm; unsigned* mn; int g;
  if (wid < 2048) { g = wid;        src = x; dst = Xf; nrm = xx; mn = rowmin; }
  else            { g = wid - 2048; src = y; dst = Yf; nrm = yy; mn = colmin; }

  unsigned char* tw = T[wv];
  const float* rp = src + (size_t)g * 16 * D_;
#pragma unroll
  for (int r = 0; r < 16; ++r) {
    float4 v = *(const float4*)(rp + r * D_ + lane * 4);   // 1 KB contiguous
    unsigned u = __builtin_amdgcn_cvt_pk_fp8_f32(v.x, v.y, 0, 0);
    u = __builtin_amdgcn_cvt_pk_fp8_f32(v.z, v.w, u, 1);   // bytes = x,y,z,w
    *(unsigned*)(tw + r * 272 + lane * 4) = u;
  }
  // Each wave only reads its own T[wv] slice; all cross-lane traffic is
  // intra-wave, so a wave-local lgkmcnt drain replaces the 4-wave rendezvous.
  asm volatile("s_waitcnt lgkmcnt(0)" ::: "memory");
  __builtin_amdgcn_wave_barrier();

  // fragment-order readback: row = lane&15, k-base = (lane>>4)*32
  float s = 0.f;
  const int row = lane & 15, ko = (lane >> 4) * 32;
#pragma unroll
  for (int kt = 0; kt < 2; ++kt)
#pragma unroll
    for (int h = 0; h < 2; ++h) {
      uint4 c = *(const uint4*)(tw + row * 272 + kt * 128 + ko + h * 16);
      s += sq8(c.x) + sq8(c.y) + sq8(c.z) + sq8(c.w);
      *(uint4*)(dst + ((((size_t)g * 2 + kt) * 2 + h) << 10) + lane * 16) = c;
    }
  s += __shfl_xor(s, 16, 64);   // fold quads: row (lane&15)'s full norm
  s += __shfl_xor(s, 32, 64);
  if      (lane < 16) nrm[g * 16 + lane] = s;
  else if (lane < 32) mn[g * 16 + lane - 16] = 0x7f800000u;   // +inf
}

// MX-fp8 chamfer GEMM (mfma_scale_f32_16x16x128_f8f6f4, scales = 1.0).
// Round-21: r19 structure restored (ROLLED p-loop -- r20's full unroll blew
// the register envelope: VGPR 128 + 413 MB spill FETCH, 3rd spill incident;
// scheduling scope across ct boundaries is the wall). Kept from r20's
// intent, applied locally: (1) setprio removed (m190: harms lockstep GEMM;
// all T5 attempts here nulled); (2) min3-fusable epilogue -- rowmin takes
// both j candidates per v_min3, colmin chains eat 2 values/step, one shared
// xv pass. ~40-50 fewer VALU insts/ct at unchanged scheduling scope.
// Law from 10 rounds: dur = (T_mfma + T_valu)/0.69 (issue cap); T_mfma
// fixed at ~14 us; this round cuts T_valu only.
__global__ __launch_bounds__(256, 2) void chamfer_gemm(
    const unsigned char* __restrict__ Xf, const unsigned char* __restrict__ Yf,
    const float* __restrict__ xx, const float* __restrict__ yy,
    unsigned* __restrict__ rowmin, unsigned* __restrict__ colmin)
{
  __shared__ unsigned cmin_s[512];                     // col-min table
  __shared__ float    yys[512];                        // yy slice (LDS, low-lat)

  const int bid = blockIdx.x;
  const int b   = bid & 7;                   // batch == XCD (L2 locality)
  const int rt  = (bid >> 3) & 15;           // 16 row-tiles of 256
  const int cq  = bid >> 7;                  // 0..7 col-eighths of 512
  const int n0  = rt * 256;
  const int m0  = cq * 512;

  const int t = threadIdx.x, lane = t & 63, wave = t >> 6;
  const int quad = lane >> 4, lcol = lane & 15;

  cmin_s[t]       = 0x7f800000u;
  cmin_s[t + 256] = 0x7f800000u;
  const float* yyp = yy + b * N_ + m0;
  if (t < 128)   // 512 floats = 2 KB
    gl_lds16((const unsigned char*)yyp + t * 16, (unsigned char*)yys + t * 16);

  // ---- A fragments -> registers (coalesced dwordx4 from fragment blob) ----
  // wave owns 64 rows: g16 = b*256 + rt*16 + wave*4 + i, i = 0..3
  i32x8 af[4][2];
#pragma unroll
  for (int i = 0; i < 4; ++i) {
    const size_t g = (size_t)(b * 256 + rt * 16 + wave * 4 + i);
#pragma unroll
    for (int kt = 0; kt < 2; ++kt) {
      const uint4* p = (const uint4*)(Xf + ((g * 2 + kt) << 11));
      uint4* h = (uint4*)&af[i][kt];
      h[0] = p[lane];        // h=0
      h[1] = p[64 + lane];   // h=1
    }
  }

  float xv[4][4], rmin[4][4];
  const float* xxp = xx + b * N_ + n0 + wave * 64;
#pragma unroll
  for (int i = 0; i < 4; ++i)
#pragma unroll
    for (int r = 0; r < 4; ++r) {
      xv[i][r] = xxp[i * 16 + quad * 4 + r];
      rmin[i][r] = 1e30f;
    }

  __syncthreads();   // publish cmin init + yys (drains the gl_lds); the ONLY
                     // pre-flush barrier -- the ct loop below has none.

  // B source: ct = 32 cols = 2 contiguous g16 blobs = 8 KB, L2-resident.
  const unsigned char* Ybase = Yf + ((size_t)(b * 256 + cq * 32) << 12);
  const f32x4 z4 = {0.f, 0.f, 0.f, 0.f};   // C-in for kt=0 (no acc zeroing)

  // load one ct's B fragments into a named register set (static indices)
  auto LOADB = [&](i32x8 (&bq)[2][2], int ct) {
    const unsigned char* Yct = Ybase + ((size_t)ct << 13);
#pragma unroll
    for (int j = 0; j < 2; ++j)
#pragma unroll
      for (int kt = 0; kt < 2; ++kt) {
        uint4* h = (uint4*)&bq[j][kt];
        h[0] = *(const uint4*)(Yct + j * 4096 + kt * 2048 + lane * 16);
        h[1] = *(const uint4*)(Yct + j * 4096 + kt * 2048 + 1024 + lane * 16);
      }
  };

  auto COMPUTE = [&](i32x8 (&bq)[2][2], int ct) {
    f32x4 acc[4][2];
#pragma unroll
    for (int i = 0; i < 4; ++i)
#pragma unroll
      for (int j = 0; j < 2; ++j)
        acc[i][j] = __builtin_amdgcn_mfma_scale_f32_16x16x128_f8f6f4(
            af[i][0], bq[j][0], z4,        // kt=0: C = 0 constant
            0, 0, 0, 127, 0, 127);
#pragma unroll
    for (int i = 0; i < 4; ++i)
#pragma unroll
      for (int j = 0; j < 2; ++j)
        acc[i][j] = __builtin_amdgcn_mfma_scale_f32_16x16x128_f8f6f4(
            af[i][1], bq[j][1], acc[i][j], // kt=1: accumulate
            0, 0, 0, 127, 0, 127);

    // epilogue (min3-fusable): C/D row = i*16 + quad*4 + r, col = j*16+lcol
    float yv0 = yys[ct * 32 + lcol];
    float yv1 = yys[ct * 32 + 16 + lcol];
    float cm0 = 1e30f, cm1 = 1e30f;
#pragma unroll
    for (int i = 0; i < 4; ++i)
#pragma unroll
      for (int r = 0; r < 4; r += 2) {       // 2 rows/step -> min3 chains
        float a0 = acc[i][0][r],     a1 = acc[i][1][r];
        float b0 = acc[i][0][r + 1], b1 = acc[i][1][r + 1];
        // rowmin: both j candidates fold into one v_min3 with the running min
        rmin[i][r] = fminf(fminf(rmin[i][r],
                       __builtin_fmaf(-2.f, a0, yv0)),
                       __builtin_fmaf(-2.f, a1, yv1));
        rmin[i][r + 1] = fminf(fminf(rmin[i][r + 1],
                           __builtin_fmaf(-2.f, b0, yv0)),
                           __builtin_fmaf(-2.f, b1, yv1));
        // colmin chains: 2 values per fminf(fminf()) -> v_min3
        float xr = xv[i][r], xs = xv[i][r + 1];
        cm0 = fminf(fminf(cm0, __builtin_fmaf(-2.f, a0, xr)),
                    __builtin_fmaf(-2.f, b0, xs));
        cm1 = fminf(fminf(cm1, __builtin_fmaf(-2.f, a1, xr)),
                    __builtin_fmaf(-2.f, b1, xs));
      }
    // 64-lane fire-and-forget; quads merge inside the one ds_min issue
    atomicMin(&cmin_s[ct * 32 + lcol],      __float_as_uint(cm0 + yv0));
    atomicMin(&cmin_s[ct * 32 + 16 + lcol], __float_as_uint(cm1 + yv1));
  };

  // 2-deep register pipeline (ROLLED): loads for ct+1 issue before ct's MFMA
  // cluster; compiler's counted vmcnt keeps them in flight across compute.
  i32x8 bqA[2][2], bqB[2][2];
  LOADB(bqA, 0);
  for (int p = 0; p < 8; ++p) {
    const int ct0 = 2 * p, ct1 = 2 * p + 1;
    LOADB(bqB, ct1);
    COMPUTE(bqA, ct0);
    LOADB(bqA, (ct1 + 1) & 15);   // p=7 wraps to ct0 (dead value, in-bounds)
    COMPUTE(bqB, ct1);
  }

  // rowmin: one global atomic set per block (64 rows/wave)
#pragma unroll
  for (int i = 0; i < 4; ++i)
#pragma unroll
    for (int r = 0; r < 4; ++r) {
      float v = xv[i][r] + rmin[i][r];
#pragma unroll
      for (int m = 1; m < 16; m <<= 1) v = fminf(v, __shfl_xor(v, m, 64));
      if (lcol == 0)
        atomicMin(rowmin + b * N_ + n0 + wave * 64 + i * 16 + quad * 4 + r,
                  __float_as_uint(v));
    }

  __syncthreads();
  // colmin: flush LDS table to global
#pragma unroll
  for (int i = 0; i < 2; ++i) {
    int idx = t + i * 256;
    atomicMin(colmin + b * N_ + m0 + idx, cmin_s[idx]);
  }
}

// 64 blocks x 256 threads: 16384 uint4 = 65536 mins; wave-reduce + atomicAdd.
__global__ __launch_bounds__(256) void reduce_kernel(
    const unsigned* __restrict__ mins,   // rowmin then colmin, contiguous
    float* __restrict__ out)
{
  int idx = blockIdx.x * 256 + threadIdx.x;
  uint4 u = ((const uint4*)mins)[idx];
  float s = __uint_as_float(u.x) + __uint_as_float(u.y)
          + __uint_as_float(u.z) + __uint_as_float(u.w);
#pragma unroll
  for (int m = 1; m < 64; m <<= 1) s += __shfl_xor(s, m, 64);
  if ((threadIdx.x & 63) == 0) atomicAdd(out, s);
}

extern "C" void kernel_launch(void* const* d_in, const int* in_sizes, int n_in,
                              void* d_out, int out_size, void* d_ws, size_t ws_size,
                              hipStream_t stream) {
  const float* gts   = (const float*)d_in[0];   // [8,4096,256] fp32
  const float* preds = (const float*)d_in[1];   // [8,4096,256] fp32

  char* ws = (char*)d_ws;
  const size_t XB_BYTES = (size_t)B_ * N_ * D_;         // 8 MiB each (fp8)
  unsigned char* Xf     = (unsigned char*)ws;
  unsigned char* Yf     = (unsigned char*)(ws + XB_BYTES);
  float*    xx     = (float*)(ws + 2 * XB_BYTES);
  float*    yy     = (float*)(ws + 2 * XB_BYTES + (size_t)B_ * N_ * 4);
  unsigned* rowmin = (unsigned*)(ws + 2 * XB_BYTES + (size_t)B_ * N_ * 8);
  unsigned* colmin = (unsigned*)(ws + 2 * XB_BYTES + (size_t)B_ * N_ * 12);

  // 4096 row-groups of 16 (X then Y), one wave each -> 1024 blocks
  prep_kernel<<<1024, 256, 0, stream>>>(gts, preds, Xf, Yf, xx, yy, rowmin, colmin,
                                        (float*)d_out);

  // 8 batches x 16 row-tiles(256) x 8 col-eighths(512) = 1024 blocks
  chamfer_gemm<<<1024, 256, 0, stream>>>(Xf, Yf, xx, yy, rowmin, colmin);

  reduce_kernel<<<64, 256, 0, stream>>>(rowmin, (float*)d_out);
}

// Round 12
// 132.344 us; speedup vs baseline: 3.1441x; 1.0077x over previous
//
#include <hip/hip_runtime.h>

typedef int   i32x8 __attribute__((ext_vector_type(8)));
typedef float f32x4 __attribute__((ext_vector_type(4)));

#define B_   8
#define N_   4096
#define D_   256

// fp8 fragment-major blob layout:
//   blob[g16][kt][h] = 1 KB chunk; lane l's 16 bytes at +l*16 hold
//   P[g16*16 + (l&15)][k = kt*128 + (l>>4)*32 + h*16 .. +16]  (e4m3)

__device__ __forceinline__ void gl_lds16(const void* g, void* l) {
  __builtin_amdgcn_global_load_lds(
      (const __attribute__((address_space(1))) unsigned int*)g,
      (__attribute__((address_space(3))) unsigned int*)l, 16, 0, 0);
}

// sum of squares of the 4 e4m3 bytes in w (selector must be a literal)
__device__ __forceinline__ float sq8(unsigned w) {
  float f0 = __builtin_amdgcn_cvt_f32_fp8(w, 0);
  float f1 = __builtin_amdgcn_cvt_f32_fp8(w, 1);
  float f2 = __builtin_amdgcn_cvt_f32_fp8(w, 2);
  float f3 = __builtin_amdgcn_cvt_f32_fp8(w, 3);
  return f0 * f0 + f1 * f1 + f2 * f2 + f3 * f3;
}

// One wave per 16-row group: fp32 -> fp8 e4m3 convert (coalesced 1 KB float4
// reads), in-wave LDS transpose to fragment-major, norms of DEQUANTIZED
// values accumulated during readback, min-init.
__global__ __launch_bounds__(256) void prep_kernel(
    const float* __restrict__ x, const float* __restrict__ y,
    unsigned char* __restrict__ Xf, unsigned char* __restrict__ Yf,
    float* __restrict__ xx, float* __restrict__ yy,
    unsigned* __restrict__ rowmin, unsigned* __restrict__ colmin,
    float* __restrict__ out)
{
  __shared__ unsigned char T[4][16 * 272];   // 16 rows x 256B fp8 (+16 pad)
  if (blockIdx.x == 0 && threadIdx.x == 0) out[0] = 0.f;

  const int wv = threadIdx.x >> 6, lane = threadIdx.x & 63;
  const int wid = (blockIdx.x << 2) + wv;          // 0..4095

  const float* src; unsigned char* dst; float* nrm; unsigned* mn; int g;
  if (wid < 2048) { g = wid;        src = x; dst = Xf; nrm = xx; mn = rowmin; }
  else            { g = wid - 2048; src = y; dst = Yf; nrm = yy; mn = colmin; }

  unsigned char* tw = T[wv];
  const float* rp = src + (size_t)g * 16 * D_;
#pragma unroll
  for (int r = 0; r < 16; ++r) {
    float4 v = *(const float4*)(rp + r * D_ + lane * 4);   // 1 KB contiguous
    unsigned u = __builtin_amdgcn_cvt_pk_fp8_f32(v.x, v.y, 0, 0);
    u = __builtin_amdgcn_cvt_pk_fp8_f32(v.z, v.w, u, 1);   // bytes = x,y,z,w
    *(unsigned*)(tw + r * 272 + lane * 4) = u;
  }
  // Each wave only reads its own T[wv] slice; all cross-lane traffic is
  // intra-wave, so a wave-local lgkmcnt drain replaces the 4-wave rendezvous.
  asm volatile("s_waitcnt lgkmcnt(0)" ::: "memory");
  __builtin_amdgcn_wave_barrier();

  // fragment-order readback: row = lane&15, k-base = (lane>>4)*32
  float s = 0.f;
  const int row = lane & 15, ko = (lane >> 4) * 32;
#pragma unroll
  for (int kt = 0; kt < 2; ++kt)
#pragma unroll
    for (int h = 0; h < 2; ++h) {
      uint4 c = *(const uint4*)(tw + row * 272 + kt * 128 + ko + h * 16);
      s += sq8(c.x) + sq8(c.y) + sq8(c.z) + sq8(c.w);
      *(uint4*)(dst + ((((size_t)g * 2 + kt) * 2 + h) << 10) + lane * 16) = c;
    }
  s += __shfl_xor(s, 16, 64);   // fold quads: row (lane&15)'s full norm
  s += __shfl_xor(s, 32, 64);
  if      (lane < 16) nrm[g * 16 + lane] = s;
  else if (lane < 32) mn[g * 16 + lane - 16] = 0x7f800000u;   // +inf
}

// MX-fp8 chamfer GEMM (mfma_scale_f32_16x16x128_f8f6f4, scales = 1.0).
// Round-22: A/B decomposition of r21's confounded regression (r21 = r19
// - setprio + min3-epilogue -> 44.8 us vs r19's 41.0; both pipe-times
// unchanged, dead time grew). Suspect: setprio removal. m190's setprio-harm
// was measured on a LOCKSTEP barrier-synced GEMM; this barrier-free
// independent-wave loop has real phase diversity (waves drift through ct),
// the T5-paying regime (m218b). This round: setprio RESTORED around the
// MFMA cluster, min3 epilogue KEPT. One variable vs r21; decodes vs r19:
// ~39 -> both changes good; ~41 -> diet neutral; ~44 -> min3 bad, r19 is
// the ceiling.
__global__ __launch_bounds__(256, 2) void chamfer_gemm(
    const unsigned char* __restrict__ Xf, const unsigned char* __restrict__ Yf,
    const float* __restrict__ xx, const float* __restrict__ yy,
    unsigned* __restrict__ rowmin, unsigned* __restrict__ colmin)
{
  __shared__ unsigned cmin_s[512];                     // col-min table
  __shared__ float    yys[512];                        // yy slice (LDS, low-lat)

  const int bid = blockIdx.x;
  const int b   = bid & 7;                   // batch == XCD (L2 locality)
  const int rt  = (bid >> 3) & 15;           // 16 row-tiles of 256
  const int cq  = bid >> 7;                  // 0..7 col-eighths of 512
  const int n0  = rt * 256;
  const int m0  = cq * 512;

  const int t = threadIdx.x, lane = t & 63, wave = t >> 6;
  const int quad = lane >> 4, lcol = lane & 15;

  cmin_s[t]       = 0x7f800000u;
  cmin_s[t + 256] = 0x7f800000u;
  const float* yyp = yy + b * N_ + m0;
  if (t < 128)   // 512 floats = 2 KB
    gl_lds16((const unsigned char*)yyp + t * 16, (unsigned char*)yys + t * 16);

  // ---- A fragments -> registers (coalesced dwordx4 from fragment blob) ----
  // wave owns 64 rows: g16 = b*256 + rt*16 + wave*4 + i, i = 0..3
  i32x8 af[4][2];
#pragma unroll
  for (int i = 0; i < 4; ++i) {
    const size_t g = (size_t)(b * 256 + rt * 16 + wave * 4 + i);
#pragma unroll
    for (int kt = 0; kt < 2; ++kt) {
      const uint4* p = (const uint4*)(Xf + ((g * 2 + kt) << 11));
      uint4* h = (uint4*)&af[i][kt];
      h[0] = p[lane];        // h=0
      h[1] = p[64 + lane];   // h=1
    }
  }

  float xv[4][4], rmin[4][4];
  const float* xxp = xx + b * N_ + n0 + wave * 64;
#pragma unroll
  for (int i = 0; i < 4; ++i)
#pragma unroll
    for (int r = 0; r < 4; ++r) {
      xv[i][r] = xxp[i * 16 + quad * 4 + r];
      rmin[i][r] = 1e30f;
    }

  __syncthreads();   // publish cmin init + yys (drains the gl_lds); the ONLY
                     // pre-flush barrier -- the ct loop below has none.

  // B source: ct = 32 cols = 2 contiguous g16 blobs = 8 KB, L2-resident.
  const unsigned char* Ybase = Yf + ((size_t)(b * 256 + cq * 32) << 12);
  const f32x4 z4 = {0.f, 0.f, 0.f, 0.f};   // C-in for kt=0 (no acc zeroing)

  // load one ct's B fragments into a named register set (static indices)
  auto LOADB = [&](i32x8 (&bq)[2][2], int ct) {
    const unsigned char* Yct = Ybase + ((size_t)ct << 13);
#pragma unroll
    for (int j = 0; j < 2; ++j)
#pragma unroll
      for (int kt = 0; kt < 2; ++kt) {
        uint4* h = (uint4*)&bq[j][kt];
        h[0] = *(const uint4*)(Yct + j * 4096 + kt * 2048 + lane * 16);
        h[1] = *(const uint4*)(Yct + j * 4096 + kt * 2048 + 1024 + lane * 16);
      }
  };

  auto COMPUTE = [&](i32x8 (&bq)[2][2], int ct) {
    f32x4 acc[4][2];
    __builtin_amdgcn_s_setprio(1);
#pragma unroll
    for (int i = 0; i < 4; ++i)
#pragma unroll
      for (int j = 0; j < 2; ++j)
        acc[i][j] = __builtin_amdgcn_mfma_scale_f32_16x16x128_f8f6f4(
            af[i][0], bq[j][0], z4,        // kt=0: C = 0 constant
            0, 0, 0, 127, 0, 127);
#pragma unroll
    for (int i = 0; i < 4; ++i)
#pragma unroll
      for (int j = 0; j < 2; ++j)
        acc[i][j] = __builtin_amdgcn_mfma_scale_f32_16x16x128_f8f6f4(
            af[i][1], bq[j][1], acc[i][j], // kt=1: accumulate
            0, 0, 0, 127, 0, 127);
    __builtin_amdgcn_s_setprio(0);

    // epilogue (min3-fusable): C/D row = i*16 + quad*4 + r, col = j*16+lcol
    float yv0 = yys[ct * 32 + lcol];
    float yv1 = yys[ct * 32 + 16 + lcol];
    float cm0 = 1e30f, cm1 = 1e30f;
#pragma unroll
    for (int i = 0; i < 4; ++i)
#pragma unroll
      for (int r = 0; r < 4; r += 2) {       // 2 rows/step -> min3 chains
        float a0 = acc[i][0][r],     a1 = acc[i][1][r];
        float b0 = acc[i][0][r + 1], b1 = acc[i][1][r + 1];
        // rowmin: both j candidates fold into one v_min3 with the running min
        rmin[i][r] = fminf(fminf(rmin[i][r],
                       __builtin_fmaf(-2.f, a0, yv0)),
                       __builtin_fmaf(-2.f, a1, yv1));
        rmin[i][r + 1] = fminf(fminf(rmin[i][r + 1],
                           __builtin_fmaf(-2.f, b0, yv0)),
                           __builtin_fmaf(-2.f, b1, yv1));
        // colmin chains: 2 values per fminf(fminf()) -> v_min3
        float xr = xv[i][r], xs = xv[i][r + 1];
        cm0 = fminf(fminf(cm0, __builtin_fmaf(-2.f, a0, xr)),
                    __builtin_fmaf(-2.f, b0, xs));
        cm1 = fminf(fminf(cm1, __builtin_fmaf(-2.f, a1, xr)),
                    __builtin_fmaf(-2.f, b1, xs));
      }
    // 64-lane fire-and-forget; quads merge inside the one ds_min issue
    atomicMin(&cmin_s[ct * 32 + lcol],      __float_as_uint(cm0 + yv0));
    atomicMin(&cmin_s[ct * 32 + 16 + lcol], __float_as_uint(cm1 + yv1));
  };

  // 2-deep register pipeline (ROLLED): loads for ct+1 issue before ct's MFMA
  // cluster; compiler's counted vmcnt keeps them in flight across compute.
  i32x8 bqA[2][2], bqB[2][2];
  LOADB(bqA, 0);
  for (int p = 0; p < 8; ++p) {
    const int ct0 = 2 * p, ct1 = 2 * p + 1;
    LOADB(bqB, ct1);
    COMPUTE(bqA, ct0);
    LOADB(bqA, (ct1 + 1) & 15);   // p=7 wraps to ct0 (dead value, in-bounds)
    COMPUTE(bqB, ct1);
  }

  // rowmin: one global atomic set per block (64 rows/wave)
#pragma unroll
  for (int i = 0; i < 4; ++i)
#pragma unroll
    for (int r = 0; r < 4; ++r) {
      float v = xv[i][r] + rmin[i][r];
#pragma unroll
      for (int m = 1; m < 16; m <<= 1) v = fminf(v, __shfl_xor(v, m, 64));
      if (lcol == 0)
        atomicMin(rowmin + b * N_ + n0 + wave * 64 + i * 16 + quad * 4 + r,
                  __float_as_uint(v));
    }

  __syncthreads();
  // colmin: flush LDS table to global
#pragma unroll
  for (int i = 0; i < 2; ++i) {
    int idx = t + i * 256;
    atomicMin(colmin + b * N_ + m0 + idx, cmin_s[idx]);
  }
}

// 64 blocks x 256 threads: 16384 uint4 = 65536 mins; wave-reduce + atomicAdd.
__global__ __launch_bounds__(256) void reduce_kernel(
    const unsigned* __restrict__ mins,   // rowmin then colmin, contiguous
    float* __restrict__ out)
{
  int idx = blockIdx.x * 256 + threadIdx.x;
  uint4 u = ((const uint4*)mins)[idx];
  float s = __uint_as_float(u.x) + __uint_as_float(u.y)
          + __uint_as_float(u.z) + __uint_as_float(u.w);
#pragma unroll
  for (int m = 1; m < 64; m <<= 1) s += __shfl_xor(s, m, 64);
  if ((threadIdx.x & 63) == 0) atomicAdd(out, s);
}

extern "C" void kernel_launch(void* const* d_in, const int* in_sizes, int n_in,
                              void* d_out, int out_size, void* d_ws, size_t ws_size,
                              hipStream_t stream) {
  const float* gts   = (const float*)d_in[0];   // [8,4096,256] fp32
  const float* preds = (const float*)d_in[1];   // [8,4096,256] fp32

  char* ws = (char*)d_ws;
  const size_t XB_BYTES = (size_t)B_ * N_ * D_;         // 8 MiB each (fp8)
  unsigned char* Xf     = (unsigned char*)ws;
  unsigned char* Yf     = (unsigned char*)(ws + XB_BYTES);
  float*    xx     = (float*)(ws + 2 * XB_BYTES);
  float*    yy     = (float*)(ws + 2 * XB_BYTES + (size_t)B_ * N_ * 4);
  unsigned* rowmin = (unsigned*)(ws + 2 * XB_BYTES + (size_t)B_ * N_ * 8);
  unsigned* colmin = (unsigned*)(ws + 2 * XB_BYTES + (size_t)B_ * N_ * 12);

  // 4096 row-groups of 16 (X then Y), one wave each -> 1024 blocks
  prep_kernel<<<1024, 256, 0, stream>>>(gts, preds, Xf, Yf, xx, yy, rowmin, colmin,
                                        (float*)d_out);

  // 8 batches x 16 row-tiles(256) x 8 col-eighths(512) = 1024 blocks
  chamfer_gemm<<<1024, 256, 0, stream>>>(Xf, Yf, xx, yy, rowmin, colmin);

  reduce_kernel<<<64, 256, 0, stream>>>(rowmin, (float*)d_out);
}